// Round 9
// baseline (3851.623 us; speedup 1.0000x reference)
//
#include <hip/hip_runtime.h>
#include <cstddef>
#include <cstdint>

#define B_ 32
#define T_ 1024
#define IN_ 256
#define H_ 512
#define O_ 256
#define DT_ 0.1f

typedef _Float16 f16x8 __attribute__((ext_vector_type(8)));
typedef float f32x4 __attribute__((ext_vector_type(4)));

// ---------------------------------------------------------------------------
// Generic fp32 GEMM: C[m][n] = sum_k A[m][k] * Bw[n][k],  M = 32768 fixed.
// ---------------------------------------------------------------------------
template<int N, int K, bool SWA, bool SWC>
__global__ __launch_bounds__(256, 4) void gemm128(const float* __restrict__ A,
                                                  const float* __restrict__ Bw,
                                                  float* __restrict__ C) {
    __shared__ float al[32][132];
    __shared__ float bl[32][132];
    const int tid = threadIdx.x;
    const int m0 = blockIdx.x * 128;
    const int n0 = blockIdx.y * 128;
    const int tx = tid & 15;
    const int ty = tid >> 4;
    float acc[8][8] = {};

    const int lrow = tid >> 3;
    const int kk = (tid & 7) * 4;

    for (int kc = 0; kc < K; kc += 32) {
        __syncthreads();
#pragma unroll
        for (int p = 0; p < 4; ++p) {
            const int row = lrow + p * 32;
            const int m = m0 + row;
            const size_t aoff = SWA ? ((size_t)((m & 31) * T_ + (m >> 5)) * K)
                                    : ((size_t)m * K);
            const float4 v = *(const float4*)(A + aoff + kc + kk);
            al[kk + 0][row] = v.x; al[kk + 1][row] = v.y;
            al[kk + 2][row] = v.z; al[kk + 3][row] = v.w;
        }
#pragma unroll
        for (int p = 0; p < 4; ++p) {
            const int row = lrow + p * 32;
            const float4 v = *(const float4*)(Bw + (size_t)(n0 + row) * K + kc + kk);
            bl[kk + 0][row] = v.x; bl[kk + 1][row] = v.y;
            bl[kk + 2][row] = v.z; bl[kk + 3][row] = v.w;
        }
        __syncthreads();
#pragma unroll
        for (int k = 0; k < 32; ++k) {
            float av[8], bv[8];
            *(float4*)&av[0] = *(const float4*)&al[k][ty * 8];
            *(float4*)&av[4] = *(const float4*)&al[k][ty * 8 + 4];
            *(float4*)&bv[0] = *(const float4*)&bl[k][tx * 8];
            *(float4*)&bv[4] = *(const float4*)&bl[k][tx * 8 + 4];
#pragma unroll
            for (int i = 0; i < 8; ++i)
#pragma unroll
                for (int j = 0; j < 8; ++j)
                    acc[i][j] = fmaf(av[i], bv[j], acc[i][j]);
        }
    }
#pragma unroll
    for (int i = 0; i < 8; ++i) {
        const int m = m0 + ty * 8 + i;
        const size_t coff = SWC ? ((size_t)((m & 31) * T_ + (m >> 5)) * N)
                                : ((size_t)m * N);
        const float4 v0 = make_float4(acc[i][0], acc[i][1], acc[i][2], acc[i][3]);
        const float4 v1 = make_float4(acc[i][4], acc[i][5], acc[i][6], acc[i][7]);
        *(float4*)(C + coff + n0 + tx * 8) = v0;
        *(float4*)(C + coff + n0 + tx * 8 + 4) = v1;
    }
}

// ---------------------------------------------------------------------------
// K2: a_coef[t][h] = 1 - DT / softplus(tc[h] + 0.1 * mean_b |sensory[t][b][h]|)
// ---------------------------------------------------------------------------
__global__ __launch_bounds__(512) void tau_kernel(const float* __restrict__ sens,
                                                  const float* __restrict__ tc,
                                                  float* __restrict__ acoef) {
    const int t = blockIdx.x;
    const int h = threadIdx.x;
    float s = 0.f;
#pragma unroll 8
    for (int b = 0; b < B_; ++b)
        s += fabsf(sens[((size_t)t * B_ + b) * H_ + h]);
    const float x = tc[h] + 0.1f * (s * (1.f / 32.f));
    const float sp = fmaxf(x, 0.f) + log1pf(expf(-fabsf(x)));
    acoef[(size_t)t * H_ + h] = 1.f - DT_ / sp;
}

// ---------------------------------------------------------------------------
// K3: serial scan, MFMA, ALL W in registers. 32 WGs x 512 thr (8 waves).
// Wave w owns rows 64w..64w+63 over all 512 k: 4 row-tiles x 16 k-tiles of
// v_mfma_f32_16x16x32_f16; all 64 A-frags (256 regs) live in the unified
// VGPR/AGPR file (MFMA reads AGPR natively -> zero move insts, zero W LDS).
// Per-step LDS: 16 broadcast b128 B-reads + wave-LOCAL pred (written by
// lanes lm==0 of wave w, read only by wave w's threads -> lgkmcnt(0), no
// barrier). h triple-buffered: step t reads buf (t%3), writes buf ((t+1)%3);
// ONE barrier/step bounds wave drift to <1 step, so the writer's buffer is
// always distinct from any reader's (proof: A in step t+1 writes (t+2)%3;
// any B still in step t touches t%3 / (t+1)%3, and B's (t+1)%3 write is
// ordered before barrier t which A passed). sensH global store stays in
// flight (never vmcnt-drained in-loop; proven R7).
// C/D layout (m89-verified): col=lane&15 (col 0 = real), row=(lane>>4)*4+i.
// ---------------------------------------------------------------------------
#define BARRIER_LGKM() asm volatile("s_waitcnt lgkmcnt(0)\n\ts_barrier" ::: "memory")
#define MFMA16(a, b, c) __builtin_amdgcn_mfma_f32_16x16x32_f16(a, b, c, 0, 0, 0)

__global__ __attribute__((amdgpu_flat_work_group_size(512, 512)))
void scan_kernel(const float* __restrict__ Wr, const float* __restrict__ acoef,
                 const float* __restrict__ bias, float* sensH,
                 float* __restrict__ finalh) {
    __shared__ float pred[512];
    __shared__ _Float16 h2s[3][512];

    const int tid  = threadIdx.x;
    const int b    = blockIdx.x;
    const int lane = tid & 63;
    const int w    = tid >> 6;
    const int lm   = lane & 15;      // A-row-in-tile / D-col index
    const int lq   = lane >> 4;      // k-quarter / D-row-quad index

    // --- one-time: all 64 W frags -> registers (AGPR-eligible) ---
    f16x8 wf[4][16];
#pragma unroll
    for (int kt = 0; kt < 16; ++kt) {
#pragma unroll
        for (int rt = 0; rt < 4; ++rt) {
            const int row  = w * 64 + rt * 16 + lm;
            const int col0 = kt * 32 + lq * 8;
            const float* p = Wr + (size_t)row * H_ + col0;
            const float4 v0 = *(const float4*)p;
            const float4 v1 = *(const float4*)(p + 4);
            f16x8 f;
            f[0] = (_Float16)v0.x; f[1] = (_Float16)v0.y;
            f[2] = (_Float16)v0.z; f[3] = (_Float16)v0.w;
            f[4] = (_Float16)v1.x; f[5] = (_Float16)v1.y;
            f[6] = (_Float16)v1.z; f[7] = (_Float16)v1.w;
            wf[rt][kt] = f;
        }
    }

    if (tid < 256) ((float*)&h2s[0][0])[tid] = 0.f;   // zero buffer 0
    float h_reg = 0.f;
    const float bias_r = bias[tid];
    float s_cur = sensH[(size_t)b * H_ + tid];
    float a_cur = acoef[tid];
    __syncthreads();

    const int bq = lq * 8;           // B-frag element offset within h-buffer
    int cur = 0, nxt = 1;

    for (int t = 0; t < T_; ++t) {
        const int tn = (t < T_ - 1) ? t + 1 : t;
        const float s_nxt = sensH[((size_t)tn * B_ + b) * H_ + tid];
        const float a_nxt = acoef[(size_t)tn * H_ + tid];

        const _Float16* hc = &h2s[cur][bq];

        f32x4 D0 = {0.f, 0.f, 0.f, 0.f};
        f32x4 D1 = {0.f, 0.f, 0.f, 0.f};
        f32x4 D2 = {0.f, 0.f, 0.f, 0.f};
        f32x4 D3 = {0.f, 0.f, 0.f, 0.f};

#pragma unroll
        for (int kt = 0; kt < 16; ++kt) {
            const f16x8 bk = *(const f16x8*)(hc + kt * 32);
            D0 = MFMA16(wf[0][kt], bk, D0);
            D1 = MFMA16(wf[1][kt], bk, D1);
            D2 = MFMA16(wf[2][kt], bk, D2);
            D3 = MFMA16(wf[3][kt], bk, D3);
        }

        // wave-local pred write: col-0 lanes hold rec rows (row=lq*4+i)
        if (lm == 0) {
            float* pb = pred + w * 64 + lq * 4;
            *(f32x4*)(pb +  0) = D0;
            *(f32x4*)(pb + 16) = D1;
            *(f32x4*)(pb + 32) = D2;
            *(f32x4*)(pb + 48) = D3;
        }
        asm volatile("s_waitcnt lgkmcnt(0)" ::: "memory");  // same-wave visibility

        // update: thread owns h[tid] (row w*64.. matches this wave's rows)
        {
            const float rec = pred[tid];
            const float act = tanhf(s_cur + rec + bias_r);
            h_reg = a_cur * h_reg + DT_ * act;
            sensH[((size_t)t * B_ + b) * H_ + tid] = h_reg;  // stays in flight
            h2s[nxt][tid] = (_Float16)h_reg;                 // next step's B
            s_cur = s_nxt;
            a_cur = a_nxt;
        }
        BARRIER_LGKM();   // h buffer visible to all waves; no vmcnt drain

        const int old = cur;
        cur = nxt;
        nxt = (nxt == 2) ? 0 : nxt + 1;
        (void)old;
    }
    finalh[(size_t)b * H_ + tid] = h_reg;
}

// ---------------------------------------------------------------------------
extern "C" void kernel_launch(void* const* d_in, const int* in_sizes, int n_in,
                              void* d_out, int out_size, void* d_ws, size_t ws_size,
                              hipStream_t stream) {
    const float* x    = (const float*)d_in[0];
    const float* Win  = (const float*)d_in[1];
    const float* Wr   = (const float*)d_in[2];
    const float* tc   = (const float*)d_in[3];
    const float* Wo   = (const float*)d_in[4];
    const float* bias = (const float*)d_in[5];
    float* out = (float*)d_out;

    float* sensH = (float*)d_ws;                               // [T*B][H], later hiddens
    float* acoef = sensH + (size_t)T_ * B_ * H_;               // [T][H]
    const size_t need = ((size_t)T_ * B_ * H_ + (size_t)T_ * H_) * sizeof(float);
    if (ws_size < need) return;

    // K1: sensory[t*32+b][h] = sum_i x[b][t][i] * Win[h][i]
    {
        dim3 grid(32768 / 128, H_ / 128);
        hipLaunchKernelGGL((gemm128<H_, IN_, true, false>), grid, dim3(256), 0, stream,
                           x, Win, sensH);
    }
    // K2: a_coef
    hipLaunchKernelGGL(tau_kernel, dim3(T_), dim3(H_), 0, stream, sensH, tc, acoef);
    // K3: scan
    hipLaunchKernelGGL(scan_kernel, dim3(B_), dim3(512), 0, stream,
                       Wr, acoef, bias, sensH, out + (size_t)B_ * T_ * O_);
    // K4: out[b][t][o] = sum_h hiddens[t*32+b][h] * Wo[o][h]
    {
        dim3 grid(32768 / 128, O_ / 128);
        hipLaunchKernelGGL((gemm128<O_, H_, false, true>), grid, dim3(256), 0, stream,
                           sensH, Wo, out);
    }
}

// Round 10
// 3850.406 us; speedup vs baseline: 1.0003x; 1.0003x over previous
//
#include <hip/hip_runtime.h>
#include <cstddef>
#include <cstdint>

#define B_ 32
#define T_ 1024
#define IN_ 256
#define H_ 512
#define O_ 256
#define DT_ 0.1f

typedef _Float16 f16x8 __attribute__((ext_vector_type(8)));
typedef float f32x4 __attribute__((ext_vector_type(4)));

// ---------------------------------------------------------------------------
// Generic fp32 GEMM: C[m][n] = sum_k A[m][k] * Bw[n][k],  M = 32768 fixed.
// ---------------------------------------------------------------------------
template<int N, int K, bool SWA, bool SWC>
__global__ __launch_bounds__(256, 4) void gemm128(const float* __restrict__ A,
                                                  const float* __restrict__ Bw,
                                                  float* __restrict__ C) {
    __shared__ float al[32][132];
    __shared__ float bl[32][132];
    const int tid = threadIdx.x;
    const int m0 = blockIdx.x * 128;
    const int n0 = blockIdx.y * 128;
    const int tx = tid & 15;
    const int ty = tid >> 4;
    float acc[8][8] = {};

    const int lrow = tid >> 3;
    const int kk = (tid & 7) * 4;

    for (int kc = 0; kc < K; kc += 32) {
        __syncthreads();
#pragma unroll
        for (int p = 0; p < 4; ++p) {
            const int row = lrow + p * 32;
            const int m = m0 + row;
            const size_t aoff = SWA ? ((size_t)((m & 31) * T_ + (m >> 5)) * K)
                                    : ((size_t)m * K);
            const float4 v = *(const float4*)(A + aoff + kc + kk);
            al[kk + 0][row] = v.x; al[kk + 1][row] = v.y;
            al[kk + 2][row] = v.z; al[kk + 3][row] = v.w;
        }
#pragma unroll
        for (int p = 0; p < 4; ++p) {
            const int row = lrow + p * 32;
            const float4 v = *(const float4*)(Bw + (size_t)(n0 + row) * K + kc + kk);
            bl[kk + 0][row] = v.x; bl[kk + 1][row] = v.y;
            bl[kk + 2][row] = v.z; bl[kk + 3][row] = v.w;
        }
        __syncthreads();
#pragma unroll
        for (int k = 0; k < 32; ++k) {
            float av[8], bv[8];
            *(float4*)&av[0] = *(const float4*)&al[k][ty * 8];
            *(float4*)&av[4] = *(const float4*)&al[k][ty * 8 + 4];
            *(float4*)&bv[0] = *(const float4*)&bl[k][tx * 8];
            *(float4*)&bv[4] = *(const float4*)&bl[k][tx * 8 + 4];
#pragma unroll
            for (int i = 0; i < 8; ++i)
#pragma unroll
                for (int j = 0; j < 8; ++j)
                    acc[i][j] = fmaf(av[i], bv[j], acc[i][j]);
        }
    }
#pragma unroll
    for (int i = 0; i < 8; ++i) {
        const int m = m0 + ty * 8 + i;
        const size_t coff = SWC ? ((size_t)((m & 31) * T_ + (m >> 5)) * N)
                                : ((size_t)m * N);
        const float4 v0 = make_float4(acc[i][0], acc[i][1], acc[i][2], acc[i][3]);
        const float4 v1 = make_float4(acc[i][4], acc[i][5], acc[i][6], acc[i][7]);
        *(float4*)(C + coff + n0 + tx * 8) = v0;
        *(float4*)(C + coff + n0 + tx * 8 + 4) = v1;
    }
}

// ---------------------------------------------------------------------------
// K2: a_coef[t][h] = 1 - DT / softplus(tc[h] + 0.1 * mean_b |sensory[t][b][h]|)
// ---------------------------------------------------------------------------
__global__ __launch_bounds__(512) void tau_kernel(const float* __restrict__ sens,
                                                  const float* __restrict__ tc,
                                                  float* __restrict__ acoef) {
    const int t = blockIdx.x;
    const int h = threadIdx.x;
    float s = 0.f;
#pragma unroll 8
    for (int b = 0; b < B_; ++b)
        s += fabsf(sens[((size_t)t * B_ + b) * H_ + h]);
    const float x = tc[h] + 0.1f * (s * (1.f / 32.f));
    const float sp = fmaxf(x, 0.f) + log1pf(expf(-fabsf(x)));
    acoef[(size_t)t * H_ + h] = 1.f - DT_ / sp;
}

// ---------------------------------------------------------------------------
// K3: serial scan, MFMA, ALL W in registers. 32 WGs x 512 thr (8 waves).
// Identical to R9 EXCEPT amdgpu_waves_per_eu(2,2): that attribute widens the
// per-wave register budget to the full unified 512 (256 V + 256 A), which is
// what lets the 256-reg wf[] land in AGPRs instead of scratch (R8 proved the
// allocator does this for 192 regs under the same attribute; R9 without it
// spilled: WRITE_SIZE +18 MB).
// Wave w owns rows 64w..64w+63 over all 512 k: 4 row-tiles x 16 k-tiles of
// v_mfma_f32_16x16x32_f16; MFMA reads AGPR natively -> zero move insts,
// zero W LDS traffic. Per-step LDS: 16 broadcast b128 B-reads + wave-LOCAL
// pred (lgkmcnt-only). h triple-buffered; ONE barrier/step bounds drift so
// writer buffer != any reader buffer. sensH store never drained in-loop.
// C/D layout (m89-verified): col=lane&15 (col 0 = real), row=(lane>>4)*4+i.
// ---------------------------------------------------------------------------
#define BARRIER_LGKM() asm volatile("s_waitcnt lgkmcnt(0)\n\ts_barrier" ::: "memory")
#define MFMA16(a, b, c) __builtin_amdgcn_mfma_f32_16x16x32_f16(a, b, c, 0, 0, 0)

__global__ __attribute__((amdgpu_flat_work_group_size(512, 512),
                          amdgpu_waves_per_eu(2, 2)))
void scan_kernel(const float* __restrict__ Wr, const float* __restrict__ acoef,
                 const float* __restrict__ bias, float* sensH,
                 float* __restrict__ finalh) {
    __shared__ float pred[512];
    __shared__ _Float16 h2s[3][512];

    const int tid  = threadIdx.x;
    const int b    = blockIdx.x;
    const int lane = tid & 63;
    const int w    = tid >> 6;
    const int lm   = lane & 15;      // A-row-in-tile / D-col index
    const int lq   = lane >> 4;      // k-quarter / D-row-quad index

    // --- one-time: all 64 W frags -> registers (AGPR-eligible) ---
    f16x8 wf[4][16];
#pragma unroll
    for (int kt = 0; kt < 16; ++kt) {
#pragma unroll
        for (int rt = 0; rt < 4; ++rt) {
            const int row  = w * 64 + rt * 16 + lm;
            const int col0 = kt * 32 + lq * 8;
            const float* p = Wr + (size_t)row * H_ + col0;
            const float4 v0 = *(const float4*)p;
            const float4 v1 = *(const float4*)(p + 4);
            f16x8 f;
            f[0] = (_Float16)v0.x; f[1] = (_Float16)v0.y;
            f[2] = (_Float16)v0.z; f[3] = (_Float16)v0.w;
            f[4] = (_Float16)v1.x; f[5] = (_Float16)v1.y;
            f[6] = (_Float16)v1.z; f[7] = (_Float16)v1.w;
            wf[rt][kt] = f;
        }
    }

    if (tid < 256) ((float*)&h2s[0][0])[tid] = 0.f;   // zero buffer 0
    float h_reg = 0.f;
    const float bias_r = bias[tid];
    float s_cur = sensH[(size_t)b * H_ + tid];
    float a_cur = acoef[tid];
    __syncthreads();

    const int bq = lq * 8;           // B-frag element offset within h-buffer
    int cur = 0, nxt = 1;

    for (int t = 0; t < T_; ++t) {
        const int tn = (t < T_ - 1) ? t + 1 : t;
        const float s_nxt = sensH[((size_t)tn * B_ + b) * H_ + tid];
        const float a_nxt = acoef[(size_t)tn * H_ + tid];

        const _Float16* hc = &h2s[cur][bq];

        f32x4 D0 = {0.f, 0.f, 0.f, 0.f};
        f32x4 D1 = {0.f, 0.f, 0.f, 0.f};
        f32x4 D2 = {0.f, 0.f, 0.f, 0.f};
        f32x4 D3 = {0.f, 0.f, 0.f, 0.f};

#pragma unroll
        for (int kt = 0; kt < 16; ++kt) {
            const f16x8 bk = *(const f16x8*)(hc + kt * 32);
            D0 = MFMA16(wf[0][kt], bk, D0);
            D1 = MFMA16(wf[1][kt], bk, D1);
            D2 = MFMA16(wf[2][kt], bk, D2);
            D3 = MFMA16(wf[3][kt], bk, D3);
        }

        // wave-local pred write: col-0 lanes hold rec rows (row=lq*4+i)
        if (lm == 0) {
            float* pb = pred + w * 64 + lq * 4;
            *(f32x4*)(pb +  0) = D0;
            *(f32x4*)(pb + 16) = D1;
            *(f32x4*)(pb + 32) = D2;
            *(f32x4*)(pb + 48) = D3;
        }
        asm volatile("s_waitcnt lgkmcnt(0)" ::: "memory");  // same-wave visibility

        // update: thread owns h[tid] (row w*64.. matches this wave's rows)
        {
            const float rec = pred[tid];
            const float act = tanhf(s_cur + rec + bias_r);
            h_reg = a_cur * h_reg + DT_ * act;
            sensH[((size_t)t * B_ + b) * H_ + tid] = h_reg;  // stays in flight
            h2s[nxt][tid] = (_Float16)h_reg;                 // next step's B
            s_cur = s_nxt;
            a_cur = a_nxt;
        }
        BARRIER_LGKM();   // h buffer visible to all waves; no vmcnt drain

        cur = nxt;
        nxt = (nxt == 2) ? 0 : nxt + 1;
    }
    finalh[(size_t)b * H_ + tid] = h_reg;
}

// ---------------------------------------------------------------------------
extern "C" void kernel_launch(void* const* d_in, const int* in_sizes, int n_in,
                              void* d_out, int out_size, void* d_ws, size_t ws_size,
                              hipStream_t stream) {
    const float* x    = (const float*)d_in[0];
    const float* Win  = (const float*)d_in[1];
    const float* Wr   = (const float*)d_in[2];
    const float* tc   = (const float*)d_in[3];
    const float* Wo   = (const float*)d_in[4];
    const float* bias = (const float*)d_in[5];
    float* out = (float*)d_out;

    float* sensH = (float*)d_ws;                               // [T*B][H], later hiddens
    float* acoef = sensH + (size_t)T_ * B_ * H_;               // [T][H]
    const size_t need = ((size_t)T_ * B_ * H_ + (size_t)T_ * H_) * sizeof(float);
    if (ws_size < need) return;

    // K1: sensory[t*32+b][h] = sum_i x[b][t][i] * Win[h][i]
    {
        dim3 grid(32768 / 128, H_ / 128);
        hipLaunchKernelGGL((gemm128<H_, IN_, true, false>), grid, dim3(256), 0, stream,
                           x, Win, sensH);
    }
    // K2: a_coef
    hipLaunchKernelGGL(tau_kernel, dim3(T_), dim3(H_), 0, stream, sensH, tc, acoef);
    // K3: scan
    hipLaunchKernelGGL(scan_kernel, dim3(B_), dim3(512), 0, stream,
                       Wr, acoef, bias, sensH, out + (size_t)B_ * T_ * O_);
    // K4: out[b][t][o] = sum_h hiddens[t*32+b][h] * Wo[o][h]
    {
        dim3 grid(32768 / 128, O_ / 128);
        hipLaunchKernelGGL((gemm128<O_, H_, false, true>), grid, dim3(256), 0, stream,
                           sensH, Wo, out);
    }
}